// Round 4
// baseline (172.199 us; speedup 1.0000x reference)
//
#include <hip/hip_runtime.h>

// LogicGatedSNN fused kernel for MI355X (gfx950) — round 4: pure-stream phases.
//
// Round 3 post-mortem: barrier removal didn't help (149 vs 141 us timed);
// BW capped ~3.6 TB/s both rounds with VALUBusy 7%, 0 conflicts. Evidence
// points at stream impurity: x[] reloads interleaved with the HBM streams
// (sharing vmcnt queue + thrashing L1) in one or both phases.
//
// This version compresses x into per-lane REGISTER bitmasks (x is exactly
// 0/1): a short prebuild pass reads x once (L2-hit, coalesced), packs this
// lane's 128 x-values into 4 u32. Then:
//   phase 1: PURE syn stream  + register bits -> integer spike count (exact)
//   phase 2: PURE trace stream + register bits -> RMW, nontemporal stores
// No LDS, no barriers, no x traffic in hot loops. First 4 trace loads are
// issued before the butterfly reduce to bridge the phase join.
//
// Exactness: counts are integers; scalar path uses __fmul_rn/__fadd_rn
// identical to the round-3 kernel that passed with absmax 0.0.
//
// Output layout (float32, flat): [spikes O][new_mem O][new_thr O][new_trace O*I]

constexpr int O_FEAT = 8192;
constexpr int I_FEAT = 8192;
constexpr float STATE_THR = 50.0f;

typedef float f32x4 __attribute__((ext_vector_type(4)));

__global__ __launch_bounds__(256) void snn_fused_v4(
    const float* __restrict__ x,    // [I] spike_input (0/1)
    const float* __restrict__ syn,  // [O*I] synapse_states
    const float* __restrict__ mp,   // [O] membrane_potential
    const float* __restrict__ thr,  // [O] adaptive_threshold
    const float* __restrict__ tr,   // [O*I] eligibility_trace
    float* __restrict__ out)        // [3*O + O*I]
{
    const int lane = threadIdx.x & 63;
    const int o = (blockIdx.x * blockDim.x + threadIdx.x) >> 6;  // row = global wave id
    const long long rowoff = (long long)o * I_FEAT;

    const f32x4* __restrict__ x4 = (const f32x4*)x;
    const f32x4* __restrict__ s4 = (const f32x4*)(syn + rowoff);
    const f32x4* __restrict__ t4 = (const f32x4*)(tr + rowoff);
    f32x4* __restrict__ n4 = (f32x4*)(out + 3LL * O_FEAT + rowoff);

    // Hoist the tiny scalar loads.
    const float mpv = mp[o];
    const float th  = thr[o];

    // --- Prebuild: pack this lane's 128 x-values (32 f32x4 slots) into 4 u32.
    // Coalesced, L2-resident (x is 32 KiB shared by all waves). One-time cost.
    unsigned xm[4];
#pragma unroll
    for (int c = 0; c < 4; ++c) {
        unsigned m = 0;
#pragma unroll
        for (int k = 0; k < 8; ++k) {
            const f32x4 xv = x4[(c * 8 + k) * 64 + lane];
            const unsigned nib = (xv.x != 0.0f ? 1u : 0u)
                               | (xv.y != 0.0f ? 2u : 0u)
                               | (xv.z != 0.0f ? 4u : 0u)
                               | (xv.w != 0.0f ? 8u : 0u);
            m |= nib << (k * 4);
        }
        xm[c] = m;
    }

    // --- Phase 1: PURE syn stream. cnt = #(syn>50 && x==1), exact integer.
    int cnt = 0;
#pragma unroll
    for (int c = 0; c < 4; ++c) {
        const unsigned m = xm[c];
#pragma unroll
        for (int k = 0; k < 8; ++k) {
            const f32x4 sv = s4[(c * 8 + k) * 64 + lane];
            cnt += ((m >> (k * 4 + 0)) & 1u) && (sv.x > STATE_THR) ? 1 : 0;
            cnt += ((m >> (k * 4 + 1)) & 1u) && (sv.y > STATE_THR) ? 1 : 0;
            cnt += ((m >> (k * 4 + 2)) & 1u) && (sv.z > STATE_THR) ? 1 : 0;
            cnt += ((m >> (k * 4 + 3)) & 1u) && (sv.w > STATE_THR) ? 1 : 0;
        }
    }

    // Pre-issue the first trace loads so they fly during the reduce.
    f32x4 tp[4];
#pragma unroll
    for (int k = 0; k < 4; ++k) tp[k] = t4[k * 64 + lane];

    // Butterfly reduce (int, exact): every lane gets the row count.
#pragma unroll
    for (int off = 1; off < 64; off <<= 1)
        cnt += __shfl_xor(cnt, off, 64);

    // Scalar neuron update.
    const float current = (float)cnt;  // exact (<= 8192)
    const float v_mem = __fadd_rn(__fmul_rn(mpv, 0.9f), current);
    const float s = (v_mem >= th) ? 1.0f : 0.0f;
    if (lane == 0) {
        out[o] = s;
        out[O_FEAT + o] = __fmul_rn(__fmul_rn(v_mem, 1.0f - s), 0.1f);
        float nth = __fadd_rn(th, __fmul_rn(s - 0.1f, 0.1f));
        out[2 * O_FEAT + o] = fminf(fmaxf(nth, 1.0f), 20.0f);
    }

    // --- Phase 2: PURE trace stream. new_trace = clip(tr*0.8 + s*x, 0, 5).
    // s,x in {0,1}: s*x == (bit && s) ? 1 : 0, exact.
    const bool sb = (s != 0.0f);
#pragma unroll
    for (int k = 0; k < 4; ++k) {  // preloaded batch (c=0, k=0..3)
        const unsigned m = xm[0];
        const f32x4 tv = tp[k];
        f32x4 r;
        r.x = fminf(fmaxf(__fadd_rn(__fmul_rn(tv.x, 0.8f), (((m >> (k*4+0)) & 1u) && sb) ? 1.0f : 0.0f), 0.0f), 5.0f);
        r.y = fminf(fmaxf(__fadd_rn(__fmul_rn(tv.y, 0.8f), (((m >> (k*4+1)) & 1u) && sb) ? 1.0f : 0.0f), 0.0f), 5.0f);
        r.z = fminf(fmaxf(__fadd_rn(__fmul_rn(tv.z, 0.8f), (((m >> (k*4+2)) & 1u) && sb) ? 1.0f : 0.0f), 0.0f), 5.0f);
        r.w = fminf(fmaxf(__fadd_rn(__fmul_rn(tv.w, 0.8f), (((m >> (k*4+3)) & 1u) && sb) ? 1.0f : 0.0f), 0.0f), 5.0f);
        __builtin_nontemporal_store(r, &n4[k * 64 + lane]);
    }
#pragma unroll
    for (int c = 0; c < 4; ++c) {
        const unsigned m = xm[c];
#pragma unroll
        for (int k = 0; k < 8; ++k) {
            if (c == 0 && k < 4) continue;  // compile-time skip (preloaded)
            const f32x4 tv = t4[(c * 8 + k) * 64 + lane];
            f32x4 r;
            r.x = fminf(fmaxf(__fadd_rn(__fmul_rn(tv.x, 0.8f), (((m >> (k*4+0)) & 1u) && sb) ? 1.0f : 0.0f), 0.0f), 5.0f);
            r.y = fminf(fmaxf(__fadd_rn(__fmul_rn(tv.y, 0.8f), (((m >> (k*4+1)) & 1u) && sb) ? 1.0f : 0.0f), 0.0f), 5.0f);
            r.z = fminf(fmaxf(__fadd_rn(__fmul_rn(tv.z, 0.8f), (((m >> (k*4+2)) & 1u) && sb) ? 1.0f : 0.0f), 0.0f), 5.0f);
            r.w = fminf(fmaxf(__fadd_rn(__fmul_rn(tv.w, 0.8f), (((m >> (k*4+3)) & 1u) && sb) ? 1.0f : 0.0f), 0.0f), 5.0f);
            __builtin_nontemporal_store(r, &n4[(c * 8 + k) * 64 + lane]);
        }
    }
}

extern "C" void kernel_launch(void* const* d_in, const int* in_sizes, int n_in,
                              void* d_out, int out_size, void* d_ws, size_t ws_size,
                              hipStream_t stream) {
    const float* x   = (const float*)d_in[0];  // spike_input [I]
    const float* syn = (const float*)d_in[1];  // synapse_states [O*I]
    const float* mp  = (const float*)d_in[2];  // membrane_potential [O]
    const float* th  = (const float*)d_in[3];  // adaptive_threshold [O]
    const float* tr  = (const float*)d_in[4];  // eligibility_trace [O*I]
    float* out = (float*)d_out;

    // 1 wave per row, 4 rows per 256-thread block -> 2048 blocks.
    snn_fused_v4<<<O_FEAT / 4, 256, 0, stream>>>(x, syn, mp, th, tr, out);
}

// Round 5
// 139.095 us; speedup vs baseline: 1.2380x; 1.2380x over previous
//
#include <hip/hip_runtime.h>

// LogicGatedSNN fused kernel for MI355X (gfx950) — round 5.
//
// Best-so-far was round 1 (block-per-row, x held in 32 VGPRs, pure phase-2
// trace stream, 141 us timed). Round 3/4 experiments showed: stream purity
// in phase 2 helps; a separate x-prebuild pass and big unrolled mask code
// hurt. This round keeps the r1 skeleton and makes surgical changes:
//   - x compressed to ONE u32 bitmask per thread, built inline in phase 1
//     (frees ~31 VGPRs for loads-in-flight; count = popc(xmask & smask))
//   - single __syncthreads: butterfly reduce + per-thread redundant total
//     (drops r1's second barrier and LDS broadcast)
//   - first two trace loads pre-issued before the reduce (bridge the join)
//   - nontemporal trace stores (keep L3 read-resident)
//
// Exactness: spike count is integer (popcount), any order bit-exact.
// Scalar update uses __fmul_rn/__fadd_rn as in all passing rounds.
// Phase-2 addend: s*x[i] == bit ? s : 0 exactly (s,x in {0,1}).
//
// Traffic is mandatory: syn 268MB + tr 268MB reads, trace 268MB write
// = 805 MB aggregate -> ~128 us floor at the 6.3 TB/s copy ceiling.
//
// Output layout (float32, flat): [spikes O][new_mem O][new_thr O][new_trace O*I]

constexpr int O_FEAT = 8192;
constexpr int I_FEAT = 8192;
constexpr float STATE_THR = 50.0f;

typedef float f32x4 __attribute__((ext_vector_type(4)));

__global__ __launch_bounds__(256) void snn_fused_v5(
    const float* __restrict__ x,    // [I] spike_input (0/1)
    const float* __restrict__ syn,  // [O*I] synapse_states
    const float* __restrict__ mp,   // [O] membrane_potential
    const float* __restrict__ thr,  // [O] adaptive_threshold
    const float* __restrict__ tr,   // [O*I] eligibility_trace
    float* __restrict__ out)        // [3*O + O*I]
{
    const int t = threadIdx.x;
    const int o = blockIdx.x;  // one block per output row
    const long long rowoff = (long long)o * I_FEAT;

    const f32x4* __restrict__ x4 = (const f32x4*)x;
    const f32x4* __restrict__ s4 = (const f32x4*)(syn + rowoff);
    const f32x4* __restrict__ t4 = (const f32x4*)(tr + rowoff);
    f32x4* __restrict__ n4 = (f32x4*)(out + 3LL * O_FEAT + rowoff);

    const float mpv = mp[o];   // broadcast scalar loads (single cacheline)
    const float th  = thr[o];

    // Phase 1: row = 2048 f32x4; thread t owns {t, t+256, ..., t+1792}.
    // Build x bitmask (32 bits) and syn bitmask inline; no float x kept.
    unsigned xmask = 0u, smask = 0u;
#pragma unroll
    for (int j = 0; j < 8; ++j) {
        const int idx = j * 256 + t;
        const f32x4 xv = x4[idx];   // 32 KiB, L1/L2-resident across all blocks
        const f32x4 sv = s4[idx];   // HBM stream
        const unsigned xn = (xv.x != 0.0f ? 1u : 0u) | (xv.y != 0.0f ? 2u : 0u)
                          | (xv.z != 0.0f ? 4u : 0u) | (xv.w != 0.0f ? 8u : 0u);
        const unsigned sn = (sv.x > STATE_THR ? 1u : 0u) | (sv.y > STATE_THR ? 2u : 0u)
                          | (sv.z > STATE_THR ? 4u : 0u) | (sv.w > STATE_THR ? 8u : 0u);
        xmask |= xn << (j * 4);
        smask |= sn << (j * 4);
    }
    int cnt = __popc(xmask & smask);  // exact integer partial count

    // Pre-issue first trace loads: they fly during the reduce + barrier.
    const f32x4 tp0 = t4[t];
    const f32x4 tp1 = t4[256 + t];

    // Butterfly reduce within wave (int, exact); cross-wave via one barrier.
#pragma unroll
    for (int off = 1; off < 64; off <<= 1)
        cnt += __shfl_xor(cnt, off, 64);

    __shared__ int wsum[4];
    if ((t & 63) == 0) wsum[t >> 6] = cnt;
    __syncthreads();
    const int total = ((wsum[0] + wsum[1]) + wsum[2]) + wsum[3];  // exact

    // Neuron update — all threads compute s redundantly; thread 0 stores.
    const float v_mem = __fadd_rn(__fmul_rn(mpv, 0.9f), (float)total);
    const float s = (v_mem >= th) ? 1.0f : 0.0f;
    if (t == 0) {
        out[o] = s;
        out[O_FEAT + o] = __fmul_rn(__fmul_rn(v_mem, 1.0f - s), 0.1f);
        float nth = __fadd_rn(th, __fmul_rn(s - 0.1f, 0.1f));
        out[2 * O_FEAT + o] = fminf(fmaxf(nth, 1.0f), 20.0f);
    }

    // Phase 2: PURE trace stream. new_trace = clip(tr*0.8 + (bit?s:0), 0, 5).
#pragma unroll
    for (int j = 0; j < 8; ++j) {
        const int idx = j * 256 + t;
        const f32x4 tv = (j == 0) ? tp0 : (j == 1) ? tp1 : t4[idx];
        const unsigned mb = xmask >> (j * 4);
        f32x4 r;
        r.x = fminf(fmaxf(__fadd_rn(__fmul_rn(tv.x, 0.8f), (mb & 1u) ? s : 0.0f), 0.0f), 5.0f);
        r.y = fminf(fmaxf(__fadd_rn(__fmul_rn(tv.y, 0.8f), (mb & 2u) ? s : 0.0f), 0.0f), 5.0f);
        r.z = fminf(fmaxf(__fadd_rn(__fmul_rn(tv.z, 0.8f), (mb & 4u) ? s : 0.0f), 0.0f), 5.0f);
        r.w = fminf(fmaxf(__fadd_rn(__fmul_rn(tv.w, 0.8f), (mb & 8u) ? s : 0.0f), 0.0f), 5.0f);
        __builtin_nontemporal_store(r, &n4[idx]);
    }
}

extern "C" void kernel_launch(void* const* d_in, const int* in_sizes, int n_in,
                              void* d_out, int out_size, void* d_ws, size_t ws_size,
                              hipStream_t stream) {
    const float* x   = (const float*)d_in[0];  // spike_input [I]
    const float* syn = (const float*)d_in[1];  // synapse_states [O*I]
    const float* mp  = (const float*)d_in[2];  // membrane_potential [O]
    const float* th  = (const float*)d_in[3];  // adaptive_threshold [O]
    const float* tr  = (const float*)d_in[4];  // eligibility_trace [O*I]
    float* out = (float*)d_out;

    snn_fused_v5<<<O_FEAT, 256, 0, stream>>>(x, syn, mp, th, tr, out);
}